// Round 7
// baseline (1494.026 us; speedup 1.0000x reference)
//
#include <hip/hip_runtime.h>
#include <hip/hip_bf16.h>
#include <cmath>

typedef __bf16 bf16;
typedef __attribute__((ext_vector_type(8))) __bf16 bf16x8;
typedef __attribute__((ext_vector_type(4))) __bf16 bf16x4;
typedef __attribute__((ext_vector_type(4))) float f32x4;
typedef unsigned long long ull;

#define TEMPC 65.0f
#define EPSC 1e-6f

#define GLD_LDS16(gptr, lptr)                                                             \
    __builtin_amdgcn_global_load_lds(                                                     \
        (const __attribute__((address_space(1))) unsigned int*)(gptr),                    \
        (__attribute__((address_space(3))) unsigned int*)(lptr), 16, 0, 0)

// ---------------- f32 -> bf16 convert ----------------
__global__ void conv_kernel(const float* __restrict__ s, bf16* __restrict__ d, int n)
{
    int i = (blockIdx.x * blockDim.x + threadIdx.x) * 4;
    const int stride = gridDim.x * blockDim.x * 4;
    for (; i < n; i += stride) {
        const float4 v = *(const float4*)(s + i);
        bf16x4 o;
        o[0] = (bf16)v.x; o[1] = (bf16)v.y; o[2] = (bf16)v.z; o[3] = (bf16)v.w;
        *(bf16x4*)(d + i) = o;
    }
}

// ---------------- phase A GEMM: XWb = emb[data] @ Wih^T + bih (bf16 out) ----------------
// 128x128 tile, BK=32, depth-2 counted vmcnt, pre-swizzled LDS source.
__global__ __launch_bounds__(256)
void gemm0_kernel(const int* __restrict__ idx, const bf16* __restrict__ emb,
                  const bf16* __restrict__ Wmat, const float* __restrict__ bih,
                  bf16* __restrict__ XWout)
{
    __shared__ __align__(16) bf16 As[2 * 128 * 32];
    __shared__ __align__(16) bf16 Bs[2 * 128 * 32];

    const int tid = threadIdx.x;
    const int l  = tid & 63;
    const int w  = tid >> 6;
    const int wr = w >> 1, wc = w & 1;
    const int wg = (blockIdx.x & 7) * 64 + (blockIdx.x >> 3);   // XCD swizzle
    const int mbase = (wg >> 3) * 128;
    const int nbase = (wg & 7) * 128;

    const int r0 = w * 32 + (l >> 2);
    const int csw = ((l & 3) ^ ((l >> 3) & 3)) * 16;
    const char* Bsrc0 = (const char*)Wmat + (size_t)(nbase + r0) * 2048 + csw;
    const char* Bsrc1 = (const char*)Wmat + (size_t)(nbase + r0 + 16) * 2048 + csw;
    const char* Asrc0 = (const char*)emb + (size_t)idx[mbase + r0] * 2048 + csw;
    const char* Asrc1 = (const char*)emb + (size_t)idx[mbase + r0 + 16] * 2048 + csw;

    const int frow  = l & 15;
    const int koffE = (((l >> 4) ^ ((frow >> 1) & 3)) * 8);
    const bf16* Ard = As + (wr * 64 + frow) * 32 + koffE;
    const bf16* Brd = Bs + (wc * 64 + frow) * 32 + koffE;

    auto stage = [&](int buf, int kb) {
        bf16* As_ = As + buf * 4096 + w * 1024;
        bf16* Bs_ = Bs + buf * 4096 + w * 1024;
        GLD_LDS16(Asrc0 + kb, As_);
        GLD_LDS16(Asrc1 + kb, As_ + 512);
        GLD_LDS16(Bsrc0 + kb, Bs_);
        GLD_LDS16(Bsrc1 + kb, Bs_ + 512);
    };

    stage(0, 0);
    stage(1, 64);

    f32x4 acc[4][4] = {};
    for (int k = 0; k < 32; ++k) {
        if (k == 31) asm volatile("s_waitcnt vmcnt(0)" ::: "memory");
        else         asm volatile("s_waitcnt vmcnt(4)" ::: "memory");
        __syncthreads();
        const bf16* Ab = Ard + (k & 1) * 4096;
        const bf16* Bb = Brd + (k & 1) * 4096;
        bf16x8 af[4], bfr[4];
        #pragma unroll
        for (int mt = 0; mt < 4; ++mt) af[mt]  = *(const bf16x8*)(Ab + mt * 16 * 32);
        #pragma unroll
        for (int nt = 0; nt < 4; ++nt) bfr[nt] = *(const bf16x8*)(Bb + nt * 16 * 32);
        #pragma unroll
        for (int mt = 0; mt < 4; ++mt)
            #pragma unroll
            for (int nt = 0; nt < 4; ++nt)
                acc[mt][nt] = __builtin_amdgcn_mfma_f32_16x16x32_bf16(af[mt], bfr[nt], acc[mt][nt], 0, 0, 0);
        __syncthreads();
        if (k + 2 < 32) stage(k & 1, (k + 2) * 64);
    }

    #pragma unroll
    for (int mt = 0; mt < 4; ++mt)
        #pragma unroll
        for (int nt = 0; nt < 4; ++nt) {
            const int colg = nbase + wc * 64 + nt * 16 + frow;
            const float bi = bih[colg];
            #pragma unroll
            for (int r = 0; r < 4; ++r) {
                const int rowg = mbase + wr * 64 + mt * 16 + (l >> 4) * 4 + r;
                XWout[(size_t)rowg * 1024 + colg] = (bf16)(acc[mt][nt][r] + bi);
            }
        }
}

// ---------------- MEGA kernel: RNN (256 ticket-blocks) + sampled GEMM (5120) -----------
// Tickets: first 256 arrivals run the RNN chain (resident by construction -> no deadlock);
// the rest each do one 128x128 GEMM tile, THEN wait for the RNN steps their rows need,
// acquire-fence once, and run the fused dist epilogue. 80KB LDS pool -> 2 blocks/CU.
__global__ __launch_bounds__(256, 2)
void mega_kernel(const int* __restrict__ samples, const bf16* __restrict__ emb,
                 const bf16* __restrict__ Wih, const float* __restrict__ bih,
                 const bf16* __restrict__ Whh, const float* __restrict__ bhh,
                 const bf16* __restrict__ XWb, bf16* __restrict__ raw,
                 bf16* __restrict__ Ust, float* __restrict__ dist,
                 int* __restrict__ cnt, int* __restrict__ ticket)
{
    __shared__ __align__(16) char pool[81920];
    const int tid = threadIdx.x;
    const int l   = tid & 63;
    const int w   = tid >> 6;

    int* tkp = (int*)(pool + 81912);
    if (tid == 0)
        *tkp = __hip_atomic_fetch_add(ticket, 1, __ATOMIC_RELAXED, __HIP_MEMORY_SCOPE_AGENT);
    __syncthreads();
    const int id = *tkp;
    __syncthreads();                 // everyone has id before pool is reused

    if (id < 256) {
        // ================= RNN role =================
        const int group = id & 7;
        const int slot  = id >> 3;           // 0..31
        const int jbase = slot * 32;
        const int jt    = w & 1;
        const int frow  = l & 15;
        const int kchunk = l >> 4;
        const int rr    = frow & 7;
        const int jglob = jbase + jt * 16 + frow;
        bf16* Wlds = (bf16*)pool;            // 64KB
        char* Hlds = pool + 65536;           // 16KB (XOR-swizzled)

        {   // stage Whh slice (pre-swizzled source), 4 waves split kk
            const int jloc = l >> 2;
            const int csw  = ((l & 3) ^ ((l >> 3) & 3)) * 16;
            const char* gsrc = (const char*)Whh + (size_t)(jbase + jt * 16 + jloc) * 2048 + csw;
            const int kk0 = (w >> 1) * 16;
            for (int kk = kk0; kk < kk0 + 16; ++kk)
                GLD_LDS16(gsrc + kk * 64, Wlds + (kk * 2 + jt) * 512);
            asm volatile("s_waitcnt vmcnt(0)" ::: "memory");
            __syncthreads();
        }
        const float bh = bhh[jglob];
        const float bi = bih[jglob];
        const bf16* wrd  = Wlds + jt * 512 + frow * 32 + (kchunk ^ ((frow >> 1) & 3)) * 8;
        const char* hrow = Hlds + rr * 2048;
        const int hkey = (rr & 3) << 2;
        const int hc0  = kchunk * 2;

        for (int t = 0; t < 128; ++t) {
            if (t > 0) {
                if (tid == 0)
                    while (__hip_atomic_load(&cnt[(t * 8 + group) * 16], __ATOMIC_RELAXED,
                                             __HIP_MEMORY_SCOPE_AGENT) < 32)
                        __builtin_amdgcn_s_sleep(1);
                __syncthreads();
            }
            // cooperative coherent fetch of group h_t (16KB), 256 thr x 8 x 8B
            const ull* hsrc8 = (const ull*)(raw + (size_t)t * 65536 + group * 8192);
            ull hv[8];
            #pragma unroll
            for (int i = 0; i < 8; ++i)
                hv[i] = __hip_atomic_load(hsrc8 + tid + i * 256,
                                          __ATOMIC_RELAXED, __HIP_MEMORY_SCOPE_AGENT);
            float xw[4];
            #pragma unroll
            for (int r = 0; r < 4; ++r) {
                const int bc = (kchunk * 4 + r) & 7;
                xw[r] = (float)XWb[(size_t)(t * 64 + group * 8 + bc) * 1024 + jglob];
            }
            #pragma unroll
            for (int i = 0; i < 8; ++i)
                *(ull*)(Hlds + i * 2048 + ((tid ^ ((i & 3) << 2)) * 8)) = hv[i];
            __syncthreads();

            if (w < 2) {
                f32x4 acc0 = {0.f,0.f,0.f,0.f}, acc1 = {0.f,0.f,0.f,0.f};
                #pragma unroll
                for (int kk = 0; kk < 32; kk += 2) {
                    bf16x8 a0 = *(const bf16x8*)(hrow + (((hc0 + kk * 8) ^ hkey) << 3));
                    bf16x8 a1 = *(const bf16x8*)(hrow + (((hc0 + (kk + 1) * 8) ^ hkey) << 3));
                    acc0 = __builtin_amdgcn_mfma_f32_16x16x32_bf16(a0, *(const bf16x8*)(wrd + kk * 1024),       acc0, 0, 0, 0);
                    acc1 = __builtin_amdgcn_mfma_f32_16x16x32_bf16(a1, *(const bf16x8*)(wrd + (kk + 1) * 1024), acc1, 0, 0, 0);
                }
                bf16* rawN = raw + (size_t)(t + 1) * 65536;
                if (l < 32) {
                    #pragma unroll
                    for (int r = 0; r < 4; ++r) {
                        const int b = (l >> 4) * 4 + r;
                        const float V = acc0[r] + acc1[r] + bh;
                        const float h = tanhf(xw[r] + V);
                        const size_t row = (size_t)(t * 64 + group * 8 + b);
                        const bf16 ub = (bf16)(V + bi);
                        const bf16 hb = (bf16)h;
                        unsigned short us = __builtin_bit_cast(unsigned short, ub);
                        unsigned short hs = __builtin_bit_cast(unsigned short, hb);
                        unsigned short un = (unsigned short)__shfl_down((int)us, 1, 64);
                        unsigned short hn = (unsigned short)__shfl_down((int)hs, 1, 64);
                        if ((frow & 1) == 0) {      // pack 2 cols -> coherent 4B stores
                            unsigned int up = (unsigned int)us | ((unsigned int)un << 16);
                            unsigned int hp = (unsigned int)hs | ((unsigned int)hn << 16);
                            __hip_atomic_store((unsigned int*)(Ust + row * 1024 + jglob), up,
                                               __ATOMIC_RELAXED, __HIP_MEMORY_SCOPE_AGENT);
                            __hip_atomic_store((unsigned int*)(rawN + (size_t)(group * 8 + b) * 1024 + jglob), hp,
                                               __ATOMIC_RELAXED, __HIP_MEMORY_SCOPE_AGENT);
                        }
                    }
                }
            }
            __syncthreads();                 // store acks drained (vmcnt=0 at barrier)
            if (t < 127 && tid == 0)
                __hip_atomic_fetch_add(&cnt[((t + 1) * 8 + group) * 16], 1,
                                       __ATOMIC_RELAXED, __HIP_MEMORY_SCOPE_AGENT);
        }
        if (tid == 0)                        // final signal: Ust[127] complete
            __hip_atomic_fetch_add(&cnt[(128 * 8 + group) * 16], 1,
                                   __ATOMIC_RELAXED, __HIP_MEMORY_SCOPE_AGENT);
    } else {
        // ================= GEMM role (one 128x128 tile of one sample) =================
        const int q   = id - 256;            // 0..5119
        const int mi  = q / 80;              // ascending rows -> earliest-needed first
        const int rem = q % 80;
        const int s     = rem >> 3;
        const int nbase = (rem & 7) * 128;
        const int mbase = mi * 128;

        bf16* As = (bf16*)pool;              // 16KB (2 bufs)
        bf16* Bs = (bf16*)(pool + 16384);    // 16KB
        const int wr = w >> 1, wc = w & 1;

        const int r0 = w * 32 + (l >> 2);
        const int csw = ((l & 3) ^ ((l >> 3) & 3)) * 16;
        const char* Bsrc0 = (const char*)Wih + (size_t)(nbase + r0) * 2048 + csw;
        const char* Bsrc1 = (const char*)Wih + (size_t)(nbase + r0 + 16) * 2048 + csw;
        const char* Asrc0 = (const char*)emb + (size_t)samples[s * 8192 + mbase + r0] * 2048 + csw;
        const char* Asrc1 = (const char*)emb + (size_t)samples[s * 8192 + mbase + r0 + 16] * 2048 + csw;

        const int frow  = l & 15;
        const int koffE = (((l >> 4) ^ ((frow >> 1) & 3)) * 8);
        const bf16* Ard = As + (wr * 64 + frow) * 32 + koffE;
        const bf16* Brd = Bs + (wc * 64 + frow) * 32 + koffE;

        auto stage = [&](int buf, int kb) {
            bf16* As_ = As + buf * 4096 + w * 1024;
            bf16* Bs_ = Bs + buf * 4096 + w * 1024;
            GLD_LDS16(Asrc0 + kb, As_);
            GLD_LDS16(Asrc1 + kb, As_ + 512);
            GLD_LDS16(Bsrc0 + kb, Bs_);
            GLD_LDS16(Bsrc1 + kb, Bs_ + 512);
        };

        stage(0, 0);
        stage(1, 64);

        f32x4 acc[4][4] = {};
        for (int k = 0; k < 32; ++k) {
            if (k == 31) asm volatile("s_waitcnt vmcnt(0)" ::: "memory");
            else         asm volatile("s_waitcnt vmcnt(4)" ::: "memory");
            __syncthreads();
            const bf16* Ab = Ard + (k & 1) * 4096;
            const bf16* Bb = Brd + (k & 1) * 4096;
            bf16x8 af[4], bfr[4];
            #pragma unroll
            for (int mt = 0; mt < 4; ++mt) af[mt]  = *(const bf16x8*)(Ab + mt * 16 * 32);
            #pragma unroll
            for (int nt = 0; nt < 4; ++nt) bfr[nt] = *(const bf16x8*)(Bb + nt * 16 * 32);
            #pragma unroll
            for (int mt = 0; mt < 4; ++mt)
                #pragma unroll
                for (int nt = 0; nt < 4; ++nt)
                    acc[mt][nt] = __builtin_amdgcn_mfma_f32_16x16x32_bf16(af[mt], bfr[nt], acc[mt][nt], 0, 0, 0);
            __syncthreads();
            if (k + 2 < 32) stage(k & 1, (k + 2) * 64);
        }

        // wait for RNN to finish the two steps covering rows [mbase, mbase+128)
        if (tid == 0) {
            const int widx = (mi * 2 + 2) * 8;
            for (int g = 0; g < 8; ++g)
                while (__hip_atomic_load(&cnt[(widx + g) * 16], __ATOMIC_RELAXED,
                                         __HIP_MEMORY_SCOPE_AGENT) < 32)
                    __builtin_amdgcn_s_sleep(16);
        }
        __syncthreads();
        __builtin_amdgcn_fence(__ATOMIC_ACQUIRE, "agent");   // inv caches: see Ust/raw

        #pragma unroll
        for (int mt = 0; mt < 4; ++mt)
            #pragma unroll
            for (int r = 0; r < 4; ++r) {
                const int rowg = mbase + wr * 64 + mt * 16 + (l >> 4) * 4 + r;
                float p = 0.f;
                #pragma unroll
                for (int nt = 0; nt < 4; ++nt) {
                    const int colg = nbase + wc * 64 + nt * 16 + frow;
                    const size_t e = (size_t)rowg * 1024 + colg;
                    const float o = tanhf(acc[mt][nt][r] + (float)Ust[e]);
                    const float d = (float)raw[e] - o + EPSC;   // prev = raw[rowg/64][rowg%64]
                    p += d * d;
                }
                #pragma unroll
                for (int off = 1; off < 16; off <<= 1)
                    p += __shfl_xor(p, off, 16);
                if (frow == 0) atomicAdd(&dist[s * 8192 + rowg], p);
            }
    }
}

// ---------------- pos term: (65/128) * sum (raw[t]-raw[t+1]+eps)^2 ----------------
__global__ void pos_kernel(const bf16* __restrict__ raw, float* __restrict__ lacc)
{
    float s = 0.f;
    const int NV = (128 * 64 * 1024) / 8;
    for (int i = blockIdx.x * blockDim.x + threadIdx.x; i < NV; i += gridDim.x * blockDim.x) {
        bf16x8 a = *(const bf16x8*)(raw + (size_t)i * 8);
        bf16x8 b = *(const bf16x8*)(raw + (size_t)i * 8 + 65536);
        #pragma unroll
        for (int j = 0; j < 8; ++j) {
            const float d = (float)a[j] - (float)b[j] + EPSC;
            s += d * d;
        }
    }
    #pragma unroll
    for (int off = 32; off > 0; off >>= 1) s += __shfl_down(s, off, 64);
    if ((threadIdx.x & 63) == 0) atomicAdd(lacc, s * (TEMPC / 128.f));
}

// ---------------- finalize: clip, exp, log, total ----------------
__global__ __launch_bounds__(1024)
void finalize_kernel(const float* __restrict__ dist, const float* __restrict__ lacc,
                     float* __restrict__ out)
{
    float s = 0.f;
    for (int r = threadIdx.x; r < 8192; r += 1024) {
        float se = 0.f;
        #pragma unroll
        for (int k = 0; k < 10; ++k) {
            float dd = dist[k * 8192 + r];
            dd = fminf(fmaxf(dd, 0.f), 0.01f);
            se += expf(-dd);
        }
        s += logf(se * (1.f / 8192.f) + EPSC);
    }
    #pragma unroll
    for (int off = 32; off > 0; off >>= 1) s += __shfl_down(s, off, 64);
    __shared__ float red[16];
    const int wave = threadIdx.x >> 6;
    if ((threadIdx.x & 63) == 0) red[wave] = s;
    __syncthreads();
    if (threadIdx.x == 0) {
        float tot = 0.f;
        #pragma unroll
        for (int i = 0; i < 16; ++i) tot += red[i];
        out[0] = tot + lacc[0];
    }
}

extern "C" void kernel_launch(void* const* d_in, const int* in_sizes, int n_in,
                              void* d_out, int out_size, void* d_ws, size_t ws_size,
                              hipStream_t stream)
{
    const int*   data    = (const int*)d_in[0];   // [128*64]
    const int*   samples = (const int*)d_in[1];   // [10*8192]
    const float* emb     = (const float*)d_in[2]; // [32000*1024]
    const float* Wih     = (const float*)d_in[3]; // [1024*1024]
    const float* bih     = (const float*)d_in[4]; // [1024]
    const float* Whh     = (const float*)d_in[5]; // [1024*1024]
    const float* bhh     = (const float*)d_in[6]; // [1024]

    char* ws = (char*)d_ws;
    size_t off = 0;
    auto alloc = [&](size_t bytes) { void* p = ws + off; off += (bytes + 255) & ~(size_t)255; return p; };
    bf16*  emb_b = (bf16*)alloc((size_t)32000 * 1024 * 2);
    bf16*  Wih_b = (bf16*)alloc((size_t)1024 * 1024 * 2);
    bf16*  Whh_b = (bf16*)alloc((size_t)1024 * 1024 * 2);
    bf16*  XWb   = (bf16*)alloc((size_t)8192 * 1024 * 2);
    bf16*  Ust   = (bf16*)alloc((size_t)8192 * 1024 * 2);
    bf16*  raw   = (bf16*)alloc((size_t)129 * 64 * 1024 * 2);
    float* dist  = (float*)alloc((size_t)10 * 8192 * 4);
    float* lacc  = (float*)alloc(256);
    int*   cnt   = (int*)alloc(131072);
    int*   ticket= (int*)alloc(256);

    hipMemsetAsync(raw,  0, 64 * 1024 * 2, stream);   // h0 = 0 (raw[0])
    hipMemsetAsync(dist, 0, 10 * 8192 * 4, stream);
    hipMemsetAsync(lacc, 0, 256, stream);
    hipMemsetAsync(cnt,  0, 131072, stream);          // per-(step,group) barrier counters
    hipMemsetAsync(ticket, 0, 256, stream);           // role tickets

    conv_kernel<<<2048, 256, 0, stream>>>(emb, emb_b, 32000 * 1024);
    conv_kernel<<<512, 256, 0, stream>>>(Wih, Wih_b, 1024 * 1024);
    conv_kernel<<<512, 256, 0, stream>>>(Whh, Whh_b, 1024 * 1024);

    // Phase A: XWb = emb[data] @ Wih^T + bih  (bf16)
    gemm0_kernel<<<512, 256, 0, stream>>>(data, emb_b, Wih_b, bih, XWb);

    // Phase B+D fused: RNN chain + sampled-negatives GEMM overlapped
    mega_kernel<<<5376, 256, 0, stream>>>(samples, emb_b, Wih_b, bih, Whh_b, bhh,
                                          XWb, raw, Ust, dist, cnt, ticket);

    // pos term
    pos_kernel<<<512, 256, 0, stream>>>(raw, lacc);

    finalize_kernel<<<1, 1024, 0, stream>>>(dist, lacc, (float*)d_out);
}

// Round 8
// 924.657 us; speedup vs baseline: 1.6158x; 1.6158x over previous
//
#include <hip/hip_runtime.h>
#include <hip/hip_bf16.h>
#include <cmath>

typedef __bf16 bf16;
typedef __attribute__((ext_vector_type(8))) __bf16 bf16x8;
typedef __attribute__((ext_vector_type(4))) __bf16 bf16x4;
typedef __attribute__((ext_vector_type(4))) float f32x4;
typedef unsigned long long ull;

#define TEMPC 65.0f
#define EPSC 1e-6f

#define GLD_LDS16(gptr, lptr)                                                             \
    __builtin_amdgcn_global_load_lds(                                                     \
        (const __attribute__((address_space(1))) unsigned int*)(gptr),                    \
        (__attribute__((address_space(3))) unsigned int*)(lptr), 16, 0, 0)

// ---------------- f32 -> bf16 convert ----------------
__global__ void conv_kernel(const float* __restrict__ s, bf16* __restrict__ d, int n)
{
    int i = (blockIdx.x * blockDim.x + threadIdx.x) * 4;
    const int stride = gridDim.x * blockDim.x * 4;
    for (; i < n; i += stride) {
        const float4 v = *(const float4*)(s + i);
        bf16x4 o;
        o[0] = (bf16)v.x; o[1] = (bf16)v.y; o[2] = (bf16)v.z; o[3] = (bf16)v.w;
        *(bf16x4*)(d + i) = o;
    }
}

// ---------------- BK=64 pipelined MFMA GEMM: gathered-A [128 rows] @ W^T ----------------
// 128x128 C-tile, BK=64, double-buffered LDS (64KB), depth-2 counted vmcnt(8).
// Both-sides XOR swizzle: LDS[r][x16] = G[r][x16 ^ (r&7)] (pre-swizzled global src),
// fragment reads apply the same XOR -> stride-128B ds_read_b128 is conflict-free.
// MODE 0: store XW = acc + b_ih (bf16).  MODE 1: fused dist epilogue (grid 5120).
template<int MODE>
__global__ __launch_bounds__(256)
void gemm_kernel(const int* __restrict__ idx, const bf16* __restrict__ emb,
                 const bf16* __restrict__ Wmat, const float* __restrict__ bih,
                 const bf16* __restrict__ Ust, const bf16* __restrict__ prevb,
                 bf16* __restrict__ XWout, float* __restrict__ dist)
{
    __shared__ __align__(16) bf16 As[2 * 128 * 64];   // 2 bufs x 16KB
    __shared__ __align__(16) bf16 Bs[2 * 128 * 64];

    const int tid = threadIdx.x;
    const int l  = tid & 63;
    const int w  = tid >> 6;
    const int wr = w >> 1, wc = w & 1;                // wave quadrant (64x64)

    int s, within;
    if (MODE == 0) {
        const int wg = (blockIdx.x & 7) * 64 + (blockIdx.x >> 3);   // XCD swizzle (512)
        s = 0; within = wg;
    } else {
        const int wg = (blockIdx.x & 7) * 640 + (blockIdx.x >> 3);  // XCD swizzle (5120)
        s = wg >> 9; within = wg & 511;
    }
    const int mbase = (within >> 3) * 128;
    const int nbase = (within & 7) * 128;

    // staging: 4 issues x (4 waves x 64 lanes) = 1024 16B-slots (128 rows x 8 chunks).
    // slot = i*256 + w*64 + l; r = slot>>3 = i*32 + w*8 + (l>>3); x = l&7.
    // source chunk g = x ^ (r&7) = (l&7) ^ ((l>>3)&7).
    const int g16 = ((l & 7) ^ ((l >> 3) & 7)) * 16;
    const char* Asrc[4];
    const char* Bsrc[4];
    #pragma unroll
    for (int i = 0; i < 4; ++i) {
        const int r = i * 32 + w * 8 + (l >> 3);
        Asrc[i] = (const char*)emb + (size_t)idx[s * 8192 + mbase + r] * 2048 + g16;
        Bsrc[i] = (const char*)Wmat + (size_t)(nbase + r) * 2048 + g16;
    }

    auto stage = [&](int buf, int kb) {
        char* Ad = (char*)As + buf * 16384 + w * 1024;   // +i*4096; +lane*16 implicit
        char* Bd = (char*)Bs + buf * 16384 + w * 1024;
        #pragma unroll
        for (int i = 0; i < 4; ++i) {
            GLD_LDS16(Asrc[i] + kb, Ad + i * 4096);
            GLD_LDS16(Bsrc[i] + kb, Bd + i * 4096);
        }
    };

    // fragment read geometry: row=(l&15), kchunk=(l>>4); logical chunk ks*4+kchunk,
    // stored at chunk ^ (row&7).
    const int frow = l & 15;
    const int key  = frow & 7;
    const int c0   = ((l >> 4) ^ key) * 16;      // ks=0 byte offset within row
    const int c1   = c0 ^ 64;                    // ks=1 (chunk ^ 4)
    const int rowAb = (wr * 64 + frow) * 128;    // byte offset of A fragment row
    const int rowBb = (wc * 64 + frow) * 128;

    stage(0, 0);
    stage(1, 128);

    f32x4 acc[4][4] = {};
    for (int k = 0; k < 16; ++k) {
        if (k == 15) asm volatile("s_waitcnt vmcnt(0)" ::: "memory");
        else         asm volatile("s_waitcnt vmcnt(8)" ::: "memory");  // buf k ready, k+1 flying
        __syncthreads();
        const char* Ab = (const char*)As + (k & 1) * 16384;
        const char* Bb = (const char*)Bs + (k & 1) * 16384;
        bf16x8 af0[4], af1[4], bf0[4], bf1[4];
        #pragma unroll
        for (int mt = 0; mt < 4; ++mt) {
            af0[mt] = *(const bf16x8*)(Ab + rowAb + mt * 2048 + c0);
            af1[mt] = *(const bf16x8*)(Ab + rowAb + mt * 2048 + c1);
        }
        #pragma unroll
        for (int nt = 0; nt < 4; ++nt) {
            bf0[nt] = *(const bf16x8*)(Bb + rowBb + nt * 2048 + c0);
            bf1[nt] = *(const bf16x8*)(Bb + rowBb + nt * 2048 + c1);
        }
        #pragma unroll
        for (int mt = 0; mt < 4; ++mt)
            #pragma unroll
            for (int nt = 0; nt < 4; ++nt) {
                acc[mt][nt] = __builtin_amdgcn_mfma_f32_16x16x32_bf16(af0[mt], bf0[nt], acc[mt][nt], 0, 0, 0);
                acc[mt][nt] = __builtin_amdgcn_mfma_f32_16x16x32_bf16(af1[mt], bf1[nt], acc[mt][nt], 0, 0, 0);
            }
        __syncthreads();                                  // all waves done reading buf k
        if (k + 2 < 16) stage(k & 1, (k + 2) * 128);      // refill buf k with slice k+2
    }

    if (MODE == 0) {
        #pragma unroll
        for (int mt = 0; mt < 4; ++mt)
            #pragma unroll
            for (int nt = 0; nt < 4; ++nt) {
                const int colg = nbase + wc * 64 + nt * 16 + frow;
                const float bi = bih[colg];
                #pragma unroll
                for (int r = 0; r < 4; ++r) {
                    const int rowg = mbase + wr * 64 + mt * 16 + (l >> 4) * 4 + r;
                    XWout[(size_t)rowg * 1024 + colg] = (bf16)(acc[mt][nt][r] + bi);
                }
            }
    } else {
        #pragma unroll
        for (int mt = 0; mt < 4; ++mt)
            #pragma unroll
            for (int r = 0; r < 4; ++r) {
                const int rowg = mbase + wr * 64 + mt * 16 + (l >> 4) * 4 + r;
                float p = 0.f;
                #pragma unroll
                for (int nt = 0; nt < 4; ++nt) {
                    const int colg = nbase + wc * 64 + nt * 16 + frow;
                    const size_t e = (size_t)rowg * 1024 + colg;
                    const float o = tanhf(acc[mt][nt][r] + (float)Ust[e]);
                    const float d = (float)prevb[e] - o + EPSC;
                    p += d * d;
                }
                #pragma unroll
                for (int off = 1; off < 16; off <<= 1)
                    p += __shfl_xor(p, off, 16);
                if (frow == 0) atomicAdd(&dist[s * 8192 + rowg], p);
            }
    }
}

// ---------------- fused 128-step RNN: cooperative LDS h-staging, relaxed signaling ------
// (unchanged from R6: 495 us proven)
__global__ __launch_bounds__(128, 1)
void rnn_fused(bf16* __restrict__ raw, const bf16* __restrict__ Whh,
               const bf16* __restrict__ XWb, const float* __restrict__ bih,
               const float* __restrict__ bhh, bf16* __restrict__ Ust,
               int* __restrict__ cnt)
{
    __shared__ __align__(16) bf16 Wlds[32 * 1024];       // 64KB Whh slice (swizzled)
    __shared__ __align__(16) char Hlds[8 * 2064];        // h_t: 8 rows, stride 2064B (pad)

    const int tid    = threadIdx.x;
    const int l      = tid & 63;
    const int w      = tid >> 6;            // wave = j-tile (0,1)
    const int group  = blockIdx.x & 7;      // batch group
    const int slot   = blockIdx.x >> 3;     // j-slice within group
    const int jbase  = slot * 32;
    const int frow   = l & 15;
    const int kchunk = l >> 4;
    const int jglob  = jbase + w * 16 + frow;
    const int rr     = frow & 7;            // real h row (8 rows duplicated to 16)

    // Stage Whh j-slice into LDS once, source pre-swizzled (kc ^= (j>>1)&3)
    {
        const int jloc = l >> 2;
        const int csw  = ((l & 3) ^ ((l >> 3) & 3)) * 16;
        const char* gsrc = (const char*)Whh + (size_t)(jbase + w * 16 + jloc) * 2048 + csw;
        for (int kk = 0; kk < 32; ++kk)
            GLD_LDS16(gsrc + kk * 64, Wlds + (kk * 2 + w) * 512);
        asm volatile("s_waitcnt vmcnt(0)" ::: "memory");
        __syncthreads();
    }
    const float bh = bhh[jglob];
    const float bi = bih[jglob];

    // swizzled Wlds fragment read base; +kk*1024 elements per k-block
    const int ksw   = kchunk ^ ((frow >> 1) & 3);
    const bf16* wrd = Wlds + w * 512 + frow * 32 + ksw * 8;
    // Hlds fragment read base; +kk*64 bytes per k-block
    const char* hrd = Hlds + rr * 2064 + kchunk * 16;

    for (int t = 0; t < 128; ++t) {
        if (t > 0) {
            if (tid == 0)
                while (__hip_atomic_load(&cnt[(t * 8 + group) * 16], __ATOMIC_RELAXED,
                                         __HIP_MEMORY_SCOPE_AGENT) < 32)
                    __builtin_amdgcn_s_sleep(1);
            __syncthreads();
        }
        // cooperative coherent fetch of group h_t (16KB): 128 thr x 16 x 8B, one window
        const ull* hsrc8 = (const ull*)(raw + (size_t)t * 65536 + group * 8192);
        ull hv[16];
        #pragma unroll
        for (int i = 0; i < 16; ++i)
            hv[i] = __hip_atomic_load(hsrc8 + tid + i * 128,
                                      __ATOMIC_RELAXED, __HIP_MEMORY_SCOPE_AGENT);
        // XWb for this step (cached path, latency hidden under h window)
        float xw[4];
        #pragma unroll
        for (int r = 0; r < 4; ++r) {
            const int bc = ((l >> 4) * 4 + r) & 7;
            xw[r] = (float)XWb[(size_t)(t * 64 + group * 8 + bc) * 1024 + jglob];
        }
        #pragma unroll
        for (int i = 0; i < 16; ++i) {
            const int c = tid + i * 128;                 // 256 8B-chunks per row
            *(ull*)(Hlds + (c >> 8) * 2064 + (c & 255) * 8) = hv[i];
        }
        __syncthreads();

        f32x4 acc0 = {0.f,0.f,0.f,0.f}, acc1 = {0.f,0.f,0.f,0.f};
        #pragma unroll
        for (int kk = 0; kk < 32; kk += 2) {
            bf16x8 a0 = *(const bf16x8*)(hrd + kk * 64);
            bf16x8 a1 = *(const bf16x8*)(hrd + kk * 64 + 64);
            acc0 = __builtin_amdgcn_mfma_f32_16x16x32_bf16(a0, *(const bf16x8*)(wrd + kk * 1024),       acc0, 0, 0, 0);
            acc1 = __builtin_amdgcn_mfma_f32_16x16x32_bf16(a1, *(const bf16x8*)(wrd + (kk + 1) * 1024), acc1, 0, 0, 0);
        }

        bf16* rawN = raw + (size_t)(t + 1) * 65536;
        if (l < 32) {                               // rows 0-7 real
            #pragma unroll
            for (int r = 0; r < 4; ++r) {
                const int b = (l >> 4) * 4 + r;
                const float V = acc0[r] + acc1[r] + bh;             // h @ Whh^T + b_hh
                const float h = tanhf(xw[r] + V);
                const size_t row = (size_t)(t * 64 + group * 8 + b);
                Ust[row * 1024 + jglob] = (bf16)(V + bi);           // normal store (later kernel)
                const bf16 hb = (bf16)h;
                unsigned short hs = __builtin_bit_cast(unsigned short, hb);
                unsigned short hn = (unsigned short)__shfl_down((int)hs, 1, 64);
                if ((frow & 1) == 0) {                              // pack 2 cols -> 4B store
                    unsigned int pack = (unsigned int)hs | ((unsigned int)hn << 16);
                    unsigned int* dst = (unsigned int*)(rawN + (size_t)(group * 8 + b) * 1024 + jglob);
                    __hip_atomic_store(dst, pack, __ATOMIC_RELAXED, __HIP_MEMORY_SCOPE_AGENT);
                }
            }
        }
        if (t < 127) {
            __syncthreads();                        // all waves' store acks drained here
            if (tid == 0)                           // relaxed: write-through stores already
                __hip_atomic_fetch_add(&cnt[((t + 1) * 8 + group) * 16], 1,   // at coherent pt
                                       __ATOMIC_RELAXED, __HIP_MEMORY_SCOPE_AGENT);
        }
    }
}

// ---------------- pos term: (65/128) * sum (raw[t]-raw[t+1]+eps)^2 ----------------
__global__ void pos_kernel(const bf16* __restrict__ raw, float* __restrict__ lacc)
{
    float s = 0.f;
    const int NV = (128 * 64 * 1024) / 8;
    for (int i = blockIdx.x * blockDim.x + threadIdx.x; i < NV; i += gridDim.x * blockDim.x) {
        bf16x8 a = *(const bf16x8*)(raw + (size_t)i * 8);
        bf16x8 b = *(const bf16x8*)(raw + (size_t)i * 8 + 65536);
        #pragma unroll
        for (int j = 0; j < 8; ++j) {
            const float d = (float)a[j] - (float)b[j] + EPSC;
            s += d * d;
        }
    }
    #pragma unroll
    for (int off = 32; off > 0; off >>= 1) s += __shfl_down(s, off, 64);
    if ((threadIdx.x & 63) == 0) atomicAdd(lacc, s * (TEMPC / 128.f));
}

// ---------------- finalize: clip, exp, log, total ----------------
__global__ __launch_bounds__(1024)
void finalize_kernel(const float* __restrict__ dist, const float* __restrict__ lacc,
                     float* __restrict__ out)
{
    float s = 0.f;
    for (int r = threadIdx.x; r < 8192; r += 1024) {
        float se = 0.f;
        #pragma unroll
        for (int k = 0; k < 10; ++k) {
            float dd = dist[k * 8192 + r];
            dd = fminf(fmaxf(dd, 0.f), 0.01f);
            se += expf(-dd);
        }
        s += logf(se * (1.f / 8192.f) + EPSC);
    }
    #pragma unroll
    for (int off = 32; off > 0; off >>= 1) s += __shfl_down(s, off, 64);
    __shared__ float red[16];
    const int wave = threadIdx.x >> 6;
    if ((threadIdx.x & 63) == 0) red[wave] = s;
    __syncthreads();
    if (threadIdx.x == 0) {
        float tot = 0.f;
        #pragma unroll
        for (int i = 0; i < 16; ++i) tot += red[i];
        out[0] = tot + lacc[0];
    }
}

extern "C" void kernel_launch(void* const* d_in, const int* in_sizes, int n_in,
                              void* d_out, int out_size, void* d_ws, size_t ws_size,
                              hipStream_t stream)
{
    const int*   data    = (const int*)d_in[0];   // [128*64]
    const int*   samples = (const int*)d_in[1];   // [10*8192]
    const float* emb     = (const float*)d_in[2]; // [32000*1024]
    const float* Wih     = (const float*)d_in[3]; // [1024*1024]
    const float* bih     = (const float*)d_in[4]; // [1024]
    const float* Whh     = (const float*)d_in[5]; // [1024*1024]
    const float* bhh     = (const float*)d_in[6]; // [1024]

    char* ws = (char*)d_ws;
    size_t off = 0;
    auto alloc = [&](size_t bytes) { void* p = ws + off; off += (bytes + 255) & ~(size_t)255; return p; };
    bf16*  emb_b = (bf16*)alloc((size_t)32000 * 1024 * 2);
    bf16*  Wih_b = (bf16*)alloc((size_t)1024 * 1024 * 2);
    bf16*  Whh_b = (bf16*)alloc((size_t)1024 * 1024 * 2);
    bf16*  XWb   = (bf16*)alloc((size_t)8192 * 1024 * 2);
    bf16*  Ust   = (bf16*)alloc((size_t)8192 * 1024 * 2);
    bf16*  raw   = (bf16*)alloc((size_t)129 * 64 * 1024 * 2);
    float* dist  = (float*)alloc((size_t)10 * 8192 * 4);
    float* lacc  = (float*)alloc(256);
    int*   cnt   = (int*)alloc(65536);

    hipMemsetAsync(raw,  0, 64 * 1024 * 2, stream);   // h0 = 0 (raw[0])
    hipMemsetAsync(dist, 0, 10 * 8192 * 4, stream);
    hipMemsetAsync(lacc, 0, 256, stream);
    hipMemsetAsync(cnt,  0, 65536, stream);           // per-(step,group) barrier counters

    conv_kernel<<<2048, 256, 0, stream>>>(emb, emb_b, 32000 * 1024);
    conv_kernel<<<512, 256, 0, stream>>>(Wih, Wih_b, 1024 * 1024);
    conv_kernel<<<512, 256, 0, stream>>>(Whh, Whh_b, 1024 * 1024);

    // Phase A: XWb = emb[data] @ Wih^T + bih  (bf16)
    gemm_kernel<0><<<512, 256, 0, stream>>>(data, emb_b, Wih_b, bih,
                                            nullptr, nullptr, XWb, nullptr);
    // Phase B: all 128 RNN steps, cooperative coherent h exchange
    rnn_fused<<<256, 128, 0, stream>>>(raw, Whh_b, XWb, bih, bhh, Ust, cnt);

    // pos term
    pos_kernel<<<512, 256, 0, stream>>>(raw, lacc);

    // Phase D: sampled negatives GEMM + fused dist epilogue (s flattened: 5120 blocks)
    gemm_kernel<1><<<5120, 256, 0, stream>>>(samples, emb_b, Wih_b, bih,
                                             Ust, raw, nullptr, dist);

    finalize_kernel<<<1, 1024, 0, stream>>>(dist, lacc, (float*)d_out);
}

// Round 9
// 896.012 us; speedup vs baseline: 1.6674x; 1.0320x over previous
//
#include <hip/hip_runtime.h>
#include <hip/hip_bf16.h>
#include <cmath>

typedef __bf16 bf16;
typedef __attribute__((ext_vector_type(8))) __bf16 bf16x8;
typedef __attribute__((ext_vector_type(4))) __bf16 bf16x4;
typedef __attribute__((ext_vector_type(4))) float f32x4;
typedef unsigned long long ull;

#define TEMPC 65.0f
#define EPSC 1e-6f

#define GLD_LDS16(gptr, lptr)                                                             \
    __builtin_amdgcn_global_load_lds(                                                     \
        (const __attribute__((address_space(1))) unsigned int*)(gptr),                    \
        (__attribute__((address_space(3))) unsigned int*)(lptr), 16, 0, 0)

// ---------------- f32 -> bf16 convert ----------------
__global__ void conv_kernel(const float* __restrict__ s, bf16* __restrict__ d, int n)
{
    int i = (blockIdx.x * blockDim.x + threadIdx.x) * 4;
    const int stride = gridDim.x * blockDim.x * 4;
    for (; i < n; i += stride) {
        const float4 v = *(const float4*)(s + i);
        bf16x4 o;
        o[0] = (bf16)v.x; o[1] = (bf16)v.y; o[2] = (bf16)v.z; o[3] = (bf16)v.w;
        *(bf16x4*)(d + i) = o;
    }
}

// ---------------- BK=64 pipelined MFMA GEMM with RAW barriers + counted vmcnt ----------
// 128x128 C-tile, BK=64, double-buffered LDS (64KB). KEY FIX vs R8: K-loop uses
// __builtin_amdgcn_s_barrier() (no implicit vmcnt(0) drain!) so vmcnt(8) keeps the
// next buffer's 8 loads in flight across the barrier (T3/T4). Both-sides XOR swizzle.
template<int MODE>
__global__ __launch_bounds__(256)
void gemm_kernel(const int* __restrict__ idx, const bf16* __restrict__ emb,
                 const bf16* __restrict__ Wmat, const float* __restrict__ bih,
                 const bf16* __restrict__ Ust, const bf16* __restrict__ prevb,
                 bf16* __restrict__ XWout, float* __restrict__ dist)
{
    __shared__ __align__(16) bf16 As[2 * 128 * 64];   // 2 bufs x 16KB
    __shared__ __align__(16) bf16 Bs[2 * 128 * 64];

    const int tid = threadIdx.x;
    const int l  = tid & 63;
    const int w  = tid >> 6;
    const int wr = w >> 1, wc = w & 1;                // wave quadrant (64x64)

    int s, within;
    if (MODE == 0) {
        const int wg = (blockIdx.x & 7) * 64 + (blockIdx.x >> 3);   // XCD swizzle (512)
        s = 0; within = wg;
    } else {
        const int wg = (blockIdx.x & 7) * 640 + (blockIdx.x >> 3);  // XCD swizzle (5120)
        s = wg >> 9; within = wg & 511;
    }
    const int mbase = (within >> 3) * 128;
    const int nbase = (within & 7) * 128;

    // staging: 4 issues x (4 waves x 64 lanes) = 1024 16B-slots (128 rows x 8 chunks).
    // r = i*32 + w*8 + (l>>3); source chunk = (l&7) ^ (r&7) = (l&7) ^ ((l>>3)&7).
    const int g16 = ((l & 7) ^ ((l >> 3) & 7)) * 16;
    const char* Asrc[4];
    const char* Bsrc[4];
    #pragma unroll
    for (int i = 0; i < 4; ++i) {
        const int r = i * 32 + w * 8 + (l >> 3);
        Asrc[i] = (const char*)emb + (size_t)idx[s * 8192 + mbase + r] * 2048 + g16;
        Bsrc[i] = (const char*)Wmat + (size_t)(nbase + r) * 2048 + g16;
    }

    auto stage = [&](int buf, int kb) {
        char* Ad = (char*)As + buf * 16384 + w * 1024;   // +i*4096; +lane*16 implicit
        char* Bd = (char*)Bs + buf * 16384 + w * 1024;
        #pragma unroll
        for (int i = 0; i < 4; ++i) {
            GLD_LDS16(Asrc[i] + kb, Ad + i * 4096);
            GLD_LDS16(Bsrc[i] + kb, Bd + i * 4096);
        }
    };

    // fragment read geometry: row=(l&15), chunk stored at (logical chunk) ^ (row&7)
    const int frow = l & 15;
    const int key  = frow & 7;
    const int c0   = ((l >> 4) ^ key) * 16;      // ks=0 byte offset within 128B row
    const int c1   = c0 ^ 64;                    // ks=1 (chunk ^ 4)
    const int rowAb = (wr * 64 + frow) * 128;
    const int rowBb = (wc * 64 + frow) * 128;

    stage(0, 0);
    stage(1, 128);

    f32x4 acc[4][4] = {};
    for (int k = 0; k < 16; ++k) {
        // wait for MY 8 loads of buf k (oldest); buf k+1's 8 stay in flight
        if (k == 15) asm volatile("s_waitcnt vmcnt(0)" ::: "memory");
        else         asm volatile("s_waitcnt vmcnt(8)" ::: "memory");
        __builtin_amdgcn_sched_barrier(0);
        __builtin_amdgcn_s_barrier();            // RAW: no implicit vmcnt(0) drain
        __builtin_amdgcn_sched_barrier(0);
        const char* Ab = (const char*)As + (k & 1) * 16384;
        const char* Bb = (const char*)Bs + (k & 1) * 16384;
        bf16x8 af0[4], af1[4], bf0[4], bf1[4];
        #pragma unroll
        for (int mt = 0; mt < 4; ++mt) {
            af0[mt] = *(const bf16x8*)(Ab + rowAb + mt * 2048 + c0);
            af1[mt] = *(const bf16x8*)(Ab + rowAb + mt * 2048 + c1);
        }
        #pragma unroll
        for (int nt = 0; nt < 4; ++nt) {
            bf0[nt] = *(const bf16x8*)(Bb + rowBb + nt * 2048 + c0);
            bf1[nt] = *(const bf16x8*)(Bb + rowBb + nt * 2048 + c1);
        }
        #pragma unroll
        for (int mt = 0; mt < 4; ++mt)
            #pragma unroll
            for (int nt = 0; nt < 4; ++nt) {
                acc[mt][nt] = __builtin_amdgcn_mfma_f32_16x16x32_bf16(af0[mt], bf0[nt], acc[mt][nt], 0, 0, 0);
                acc[mt][nt] = __builtin_amdgcn_mfma_f32_16x16x32_bf16(af1[mt], bf1[nt], acc[mt][nt], 0, 0, 0);
            }
        __builtin_amdgcn_sched_barrier(0);
        __builtin_amdgcn_s_barrier();            // all waves consumed buf k (data in regs)
        __builtin_amdgcn_sched_barrier(0);
        if (k + 2 < 16) stage(k & 1, (k + 2) * 128);   // refill buf k with slice k+2
    }

    if (MODE == 0) {
        #pragma unroll
        for (int mt = 0; mt < 4; ++mt)
            #pragma unroll
            for (int nt = 0; nt < 4; ++nt) {
                const int colg = nbase + wc * 64 + nt * 16 + frow;
                const float bi = bih[colg];
                #pragma unroll
                for (int r = 0; r < 4; ++r) {
                    const int rowg = mbase + wr * 64 + mt * 16 + (l >> 4) * 4 + r;
                    XWout[(size_t)rowg * 1024 + colg] = (bf16)(acc[mt][nt][r] + bi);
                }
            }
    } else {
        #pragma unroll
        for (int mt = 0; mt < 4; ++mt)
            #pragma unroll
            for (int r = 0; r < 4; ++r) {
                const int rowg = mbase + wr * 64 + mt * 16 + (l >> 4) * 4 + r;
                float p = 0.f;
                #pragma unroll
                for (int nt = 0; nt < 4; ++nt) {
                    const int colg = nbase + wc * 64 + nt * 16 + frow;
                    const size_t e = (size_t)rowg * 1024 + colg;
                    const float o = tanhf(acc[mt][nt][r] + (float)Ust[e]);
                    const float d = (float)prevb[e] - o + EPSC;
                    p += d * d;
                }
                #pragma unroll
                for (int off = 1; off < 16; off <<= 1)
                    p += __shfl_xor(p, off, 16);
                if (frow == 0) atomicAdd(&dist[s * 8192 + rowg], p);
            }
    }
}

// ---------------- fused 128-step RNN: 8 groups x 16 blocks, split counters -------------
// 128 blocks x 256 thr (1/CU). Block (group=bid&7, slot=bid>>3): batch rows
// [group*8,+8), j-cols [slot*64,+64). Whh slice LDS-resident (128KB). Step counter
// split over 4 cachelines (4 adds each, polled by 4 threads) to cut RMW contention.
__global__ __launch_bounds__(256, 1)
void rnn_fused(bf16* __restrict__ raw, const bf16* __restrict__ Whh,
               const bf16* __restrict__ XWb, const float* __restrict__ bih,
               const float* __restrict__ bhh, bf16* __restrict__ Ust,
               int* __restrict__ cnt)
{
    __shared__ __align__(16) bf16 Wlds[64 * 1024];       // 128KB Whh slice (swizzled)
    __shared__ __align__(16) char Hlds[8 * 2064];        // h_t: 8 rows, stride 2064B

    const int tid    = threadIdx.x;
    const int l      = tid & 63;
    const int w      = tid >> 6;            // wave = j-tile (0..3)
    const int group  = blockIdx.x & 7;      // batch group
    const int slot   = blockIdx.x >> 3;     // 0..15: j-slice within group
    const int jbase  = slot * 64;
    const int frow   = l & 15;
    const int kchunk = l >> 4;
    const int jglob  = jbase + w * 16 + frow;
    const int rr     = frow & 7;            // real h row (8 rows duplicated to 16)

    // Stage Whh j-slice into LDS once; wave w stages its own 16-col tile (32KB),
    // source pre-swizzled (kc ^= (j>>1)&3). Chunk (kk, jt=w) -> Wlds + (kk*4+w)*512.
    {
        const int jloc = l >> 2;
        const int csw  = ((l & 3) ^ ((l >> 3) & 3)) * 16;
        const char* gsrc = (const char*)Whh + (size_t)(jbase + w * 16 + jloc) * 2048 + csw;
        for (int kk = 0; kk < 32; ++kk)
            GLD_LDS16(gsrc + kk * 64, Wlds + (kk * 4 + w) * 512);
        asm volatile("s_waitcnt vmcnt(0)" ::: "memory");
        __syncthreads();
    }
    const float bh = bhh[jglob];
    const float bi = bih[jglob];

    // swizzled Wlds fragment read base; +kk*2048 elements per k-block
    const int ksw   = kchunk ^ ((frow >> 1) & 3);
    const bf16* wrd = Wlds + w * 512 + frow * 32 + ksw * 8;
    // Hlds fragment read base; +kk*64 bytes per k-block
    const char* hrd = Hlds + rr * 2064 + kchunk * 16;

    for (int t = 0; t < 128; ++t) {
        if (t > 0) {
            if (tid < 4)                     // parallel poll: 4 sub-counters x 4 adds
                while (__hip_atomic_load(&cnt[((t * 8 + group) * 4 + tid) * 32],
                                         __ATOMIC_RELAXED, __HIP_MEMORY_SCOPE_AGENT) < 4)
                    __builtin_amdgcn_s_sleep(1);
            __syncthreads();
        }
        // cooperative coherent fetch of group h_t (16KB): 256 thr x 8 x 8B, one window
        const ull* hsrc8 = (const ull*)(raw + (size_t)t * 65536 + group * 8192);
        ull hv[8];
        #pragma unroll
        for (int i = 0; i < 8; ++i)
            hv[i] = __hip_atomic_load(hsrc8 + tid + i * 256,
                                      __ATOMIC_RELAXED, __HIP_MEMORY_SCOPE_AGENT);
        // XWb for this step (cached path, latency hidden under h window)
        float xw[4];
        #pragma unroll
        for (int r = 0; r < 4; ++r) {
            const int bc = (kchunk * 4 + r) & 7;
            xw[r] = (float)XWb[(size_t)(t * 64 + group * 8 + bc) * 1024 + jglob];
        }
        #pragma unroll
        for (int i = 0; i < 8; ++i)
            *(ull*)(Hlds + i * 2064 + tid * 8) = hv[i];     // row i, chunk tid
        __syncthreads();

        f32x4 acc0 = {0.f,0.f,0.f,0.f}, acc1 = {0.f,0.f,0.f,0.f};
        #pragma unroll
        for (int kk = 0; kk < 32; kk += 2) {
            bf16x8 a0 = *(const bf16x8*)(hrd + kk * 64);
            bf16x8 a1 = *(const bf16x8*)(hrd + kk * 64 + 64);
            acc0 = __builtin_amdgcn_mfma_f32_16x16x32_bf16(a0, *(const bf16x8*)(wrd + kk * 2048),       acc0, 0, 0, 0);
            acc1 = __builtin_amdgcn_mfma_f32_16x16x32_bf16(a1, *(const bf16x8*)(wrd + (kk + 1) * 2048), acc1, 0, 0, 0);
        }

        bf16* rawN = raw + (size_t)(t + 1) * 65536;
        if (l < 32) {                               // rows 0-7 real
            #pragma unroll
            for (int r = 0; r < 4; ++r) {
                const int b = (l >> 4) * 4 + r;
                const float V = acc0[r] + acc1[r] + bh;             // h @ Whh^T + b_hh
                const float h = tanhf(xw[r] + V);
                const size_t row = (size_t)(t * 64 + group * 8 + b);
                Ust[row * 1024 + jglob] = (bf16)(V + bi);           // normal store
                const bf16 hb = (bf16)h;
                unsigned short hs = __builtin_bit_cast(unsigned short, hb);
                unsigned short hn = (unsigned short)__shfl_down((int)hs, 1, 64);
                if ((frow & 1) == 0) {                              // pack 2 cols -> 4B store
                    unsigned int pack = (unsigned int)hs | ((unsigned int)hn << 16);
                    unsigned int* dst = (unsigned int*)(rawN + (size_t)(group * 8 + b) * 1024 + jglob);
                    __hip_atomic_store(dst, pack, __ATOMIC_RELAXED, __HIP_MEMORY_SCOPE_AGENT);
                }
            }
        }
        if (t < 127) {
            __syncthreads();                        // all waves' store acks drained here
            if (tid == 0)                           // relaxed: stores already at coherent pt
                __hip_atomic_fetch_add(&cnt[(((t + 1) * 8 + group) * 4 + (slot & 3)) * 32], 1,
                                       __ATOMIC_RELAXED, __HIP_MEMORY_SCOPE_AGENT);
        }
    }
}

// ---------------- pos term: (65/128) * sum (raw[t]-raw[t+1]+eps)^2 ----------------
__global__ void pos_kernel(const bf16* __restrict__ raw, float* __restrict__ lacc)
{
    float s = 0.f;
    const int NV = (128 * 64 * 1024) / 8;
    for (int i = blockIdx.x * blockDim.x + threadIdx.x; i < NV; i += gridDim.x * blockDim.x) {
        bf16x8 a = *(const bf16x8*)(raw + (size_t)i * 8);
        bf16x8 b = *(const bf16x8*)(raw + (size_t)i * 8 + 65536);
        #pragma unroll
        for (int j = 0; j < 8; ++j) {
            const float d = (float)a[j] - (float)b[j] + EPSC;
            s += d * d;
        }
    }
    #pragma unroll
    for (int off = 32; off > 0; off >>= 1) s += __shfl_down(s, off, 64);
    if ((threadIdx.x & 63) == 0) atomicAdd(lacc, s * (TEMPC / 128.f));
}

// ---------------- finalize: clip, exp, log, total ----------------
__global__ __launch_bounds__(1024)
void finalize_kernel(const float* __restrict__ dist, const float* __restrict__ lacc,
                     float* __restrict__ out)
{
    float s = 0.f;
    for (int r = threadIdx.x; r < 8192; r += 1024) {
        float se = 0.f;
        #pragma unroll
        for (int k = 0; k < 10; ++k) {
            float dd = dist[k * 8192 + r];
            dd = fminf(fmaxf(dd, 0.f), 0.01f);
            se += expf(-dd);
        }
        s += logf(se * (1.f / 8192.f) + EPSC);
    }
    #pragma unroll
    for (int off = 32; off > 0; off >>= 1) s += __shfl_down(s, off, 64);
    __shared__ float red[16];
    const int wave = threadIdx.x >> 6;
    if ((threadIdx.x & 63) == 0) red[wave] = s;
    __syncthreads();
    if (threadIdx.x == 0) {
        float tot = 0.f;
        #pragma unroll
        for (int i = 0; i < 16; ++i) tot += red[i];
        out[0] = tot + lacc[0];
    }
}

extern "C" void kernel_launch(void* const* d_in, const int* in_sizes, int n_in,
                              void* d_out, int out_size, void* d_ws, size_t ws_size,
                              hipStream_t stream)
{
    const int*   data    = (const int*)d_in[0];   // [128*64]
    const int*   samples = (const int*)d_in[1];   // [10*8192]
    const float* emb     = (const float*)d_in[2]; // [32000*1024]
    const float* Wih     = (const float*)d_in[3]; // [1024*1024]
    const float* bih     = (const float*)d_in[4]; // [1024]
    const float* Whh     = (const float*)d_in[5]; // [1024*1024]
    const float* bhh     = (const float*)d_in[6]; // [1024]

    char* ws = (char*)d_ws;
    size_t off = 0;
    auto alloc = [&](size_t bytes) { void* p = ws + off; off += (bytes + 255) & ~(size_t)255; return p; };
    bf16*  emb_b = (bf16*)alloc((size_t)32000 * 1024 * 2);
    bf16*  Wih_b = (bf16*)alloc((size_t)1024 * 1024 * 2);
    bf16*  Whh_b = (bf16*)alloc((size_t)1024 * 1024 * 2);
    bf16*  XWb   = (bf16*)alloc((size_t)8192 * 1024 * 2);
    bf16*  Ust   = (bf16*)alloc((size_t)8192 * 1024 * 2);
    bf16*  raw   = (bf16*)alloc((size_t)129 * 64 * 1024 * 2);
    float* dist  = (float*)alloc((size_t)10 * 8192 * 4);
    float* lacc  = (float*)alloc(256);
    int*   cnt   = (int*)alloc(524288);

    hipMemsetAsync(raw,  0, 64 * 1024 * 2, stream);   // h0 = 0 (raw[0])
    hipMemsetAsync(dist, 0, 10 * 8192 * 4, stream);
    hipMemsetAsync(lacc, 0, 256, stream);
    hipMemsetAsync(cnt,  0, 524288, stream);          // split step-barrier counters

    conv_kernel<<<2048, 256, 0, stream>>>(emb, emb_b, 32000 * 1024);
    conv_kernel<<<512, 256, 0, stream>>>(Wih, Wih_b, 1024 * 1024);
    conv_kernel<<<512, 256, 0, stream>>>(Whh, Whh_b, 1024 * 1024);

    // Phase A: XWb = emb[data] @ Wih^T + bih  (bf16)
    gemm_kernel<0><<<512, 256, 0, stream>>>(data, emb_b, Wih_b, bih,
                                            nullptr, nullptr, XWb, nullptr);
    // Phase B: all 128 RNN steps, 8 groups x 16 blocks, split counters
    rnn_fused<<<128, 256, 0, stream>>>(raw, Whh_b, XWb, bih, bhh, Ust, cnt);

    // pos term
    pos_kernel<<<512, 256, 0, stream>>>(raw, lacc);

    // Phase D: sampled negatives GEMM + fused dist epilogue (s flattened: 5120 blocks)
    gemm_kernel<1><<<5120, 256, 0, stream>>>(samples, emb_b, Wih_b, bih,
                                             Ust, raw, nullptr, dist);

    finalize_kernel<<<1, 1024, 0, stream>>>(dist, lacc, (float*)d_out);
}

// Round 10
// 705.151 us; speedup vs baseline: 2.1187x; 1.2707x over previous
//
#include <hip/hip_runtime.h>
#include <hip/hip_bf16.h>
#include <cmath>

typedef __bf16 bf16;
typedef __attribute__((ext_vector_type(8))) __bf16 bf16x8;
typedef __attribute__((ext_vector_type(4))) __bf16 bf16x4;
typedef __attribute__((ext_vector_type(4))) float f32x4;
typedef unsigned long long ull;

#define TEMPC 65.0f
#define EPSC 1e-6f

#define GLD_LDS16(gptr, lptr)                                                             \
    __builtin_amdgcn_global_load_lds(                                                     \
        (const __attribute__((address_space(1))) unsigned int*)(gptr),                    \
        (__attribute__((address_space(3))) unsigned int*)(lptr), 16, 0, 0)

// ---------------- f32 -> bf16 convert ----------------
__global__ void conv_kernel(const float* __restrict__ s, bf16* __restrict__ d, int n)
{
    int i = (blockIdx.x * blockDim.x + threadIdx.x) * 4;
    const int stride = gridDim.x * blockDim.x * 4;
    for (; i < n; i += stride) {
        const float4 v = *(const float4*)(s + i);
        bf16x4 o;
        o[0] = (bf16)v.x; o[1] = (bf16)v.y; o[2] = (bf16)v.z; o[3] = (bf16)v.w;
        *(bf16x4*)(d + i) = o;
    }
}

// ---------------- dense P-GEMM: P = emb @ Wih^T + b_ih (bf16 out, [32000,1024]) -------
// R6-proven structure: 128x128 tile, BK=32, double-buffered LDS, depth-2 vmcnt(4),
// both-sides XOR swizzle via pre-swizzled global source. Grid 2000 (250 M x 8 N).
__global__ __launch_bounds__(256)
void pgemm_kernel(const bf16* __restrict__ A, const bf16* __restrict__ Wmat,
                  const float* __restrict__ bih, bf16* __restrict__ P)
{
    __shared__ __align__(16) bf16 As[2 * 128 * 32];   // 2 bufs x 8KB
    __shared__ __align__(16) bf16 Bs[2 * 128 * 32];

    const int tid = threadIdx.x;
    const int l  = tid & 63;
    const int w  = tid >> 6;
    const int wr = w >> 1, wc = w & 1;                 // wave quadrant (64x64)
    const int wg = (blockIdx.x & 7) * 250 + (blockIdx.x >> 3);   // XCD swizzle (2000%8==0)
    const int mbase = (wg >> 3) * 128;                 // 0..249
    const int nbase = (wg & 7) * 128;

    const int r0 = w * 32 + (l >> 2);                  // rows r0, r0+16
    const int csw = ((l & 3) ^ ((l >> 3) & 3)) * 16;   // swizzled 16B sub-chunk
    const char* Asrc0 = (const char*)A + (size_t)(mbase + r0) * 2048 + csw;
    const char* Asrc1 = (const char*)A + (size_t)(mbase + r0 + 16) * 2048 + csw;
    const char* Bsrc0 = (const char*)Wmat + (size_t)(nbase + r0) * 2048 + csw;
    const char* Bsrc1 = (const char*)Wmat + (size_t)(nbase + r0 + 16) * 2048 + csw;

    const int frow  = l & 15;
    const int koffE = (((l >> 4) ^ ((frow >> 1) & 3)) * 8);
    const bf16* Ard = As + (wr * 64 + frow) * 32 + koffE;
    const bf16* Brd = Bs + (wc * 64 + frow) * 32 + koffE;

    auto stage = [&](int buf, int kb) {
        bf16* As_ = As + buf * 4096 + w * 1024;        // wave-uniform dest (+lane*16)
        bf16* Bs_ = Bs + buf * 4096 + w * 1024;
        GLD_LDS16(Asrc0 + kb, As_);
        GLD_LDS16(Asrc1 + kb, As_ + 512);
        GLD_LDS16(Bsrc0 + kb, Bs_);
        GLD_LDS16(Bsrc1 + kb, Bs_ + 512);
    };

    stage(0, 0);
    stage(1, 64);

    f32x4 acc[4][4] = {};
    for (int k = 0; k < 32; ++k) {
        if (k == 31) asm volatile("s_waitcnt vmcnt(0)" ::: "memory");
        else         asm volatile("s_waitcnt vmcnt(4)" ::: "memory");  // buf k ready
        __syncthreads();
        const bf16* Ab = Ard + (k & 1) * 4096;
        const bf16* Bb = Brd + (k & 1) * 4096;
        bf16x8 af[4], bfr[4];
        #pragma unroll
        for (int mt = 0; mt < 4; ++mt) af[mt]  = *(const bf16x8*)(Ab + mt * 16 * 32);
        #pragma unroll
        for (int nt = 0; nt < 4; ++nt) bfr[nt] = *(const bf16x8*)(Bb + nt * 16 * 32);
        #pragma unroll
        for (int mt = 0; mt < 4; ++mt)
            #pragma unroll
            for (int nt = 0; nt < 4; ++nt)
                acc[mt][nt] = __builtin_amdgcn_mfma_f32_16x16x32_bf16(af[mt], bfr[nt], acc[mt][nt], 0, 0, 0);
        __syncthreads();
        if (k + 2 < 32) stage(k & 1, (k + 2) * 64);
    }

    #pragma unroll
    for (int mt = 0; mt < 4; ++mt)
        #pragma unroll
        for (int nt = 0; nt < 4; ++nt) {
            const int colg = nbase + wc * 64 + nt * 16 + frow;
            const float bi = bih[colg];
            #pragma unroll
            for (int r = 0; r < 4; ++r) {
                const int rowg = mbase + wr * 64 + mt * 16 + (l >> 4) * 4 + r;
                P[(size_t)rowg * 1024 + colg] = (bf16)(acc[mt][nt][r] + bi);
            }
        }
}

// ---------------- fused 128-step RNN (R9 structure, xw from P[data]) -------------------
// 128 blocks x 256 thr (1/CU). Block (group=bid&7, slot=bid>>3): batch rows
// [group*8,+8), j-cols [slot*64,+64). Whh slice LDS-resident (128KB); data tokens
// hoisted to LDS. Split step counters (4 cachelines). Ust stores V only (b_ih in P).
__global__ __launch_bounds__(256, 1)
void rnn_fused(const int* __restrict__ data, bf16* __restrict__ raw,
               const bf16* __restrict__ Whh, const bf16* __restrict__ P,
               const float* __restrict__ bhh, bf16* __restrict__ Ust,
               int* __restrict__ cnt)
{
    __shared__ __align__(16) bf16 Wlds[64 * 1024];       // 128KB Whh slice (swizzled)
    __shared__ __align__(16) char Hlds[8 * 2064];        // h_t: 8 rows, stride 2064B
    __shared__ int Tlds[1024];                           // tokens: [t 128][b 8]

    const int tid    = threadIdx.x;
    const int l      = tid & 63;
    const int w      = tid >> 6;            // wave = j-tile (0..3)
    const int group  = blockIdx.x & 7;      // batch group
    const int slot   = blockIdx.x >> 3;     // 0..15: j-slice within group
    const int jbase  = slot * 64;
    const int frow   = l & 15;
    const int kchunk = l >> 4;
    const int jglob  = jbase + w * 16 + frow;
    const int rr     = frow & 7;            // real h row (8 rows duplicated to 16)

    // hoist this group's tokens: Tlds[t*8+b] = data[t*64 + group*8 + b]
    for (int i = tid; i < 1024; i += 256)
        Tlds[i] = data[(i >> 3) * 64 + group * 8 + (i & 7)];

    // Stage Whh j-slice into LDS once; wave w stages its own 16-col tile (32KB),
    // source pre-swizzled (kc ^= (j>>1)&3). Chunk (kk, jt=w) -> Wlds + (kk*4+w)*512.
    {
        const int jloc = l >> 2;
        const int csw  = ((l & 3) ^ ((l >> 3) & 3)) * 16;
        const char* gsrc = (const char*)Whh + (size_t)(jbase + w * 16 + jloc) * 2048 + csw;
        for (int kk = 0; kk < 32; ++kk)
            GLD_LDS16(gsrc + kk * 64, Wlds + (kk * 4 + w) * 512);
        asm volatile("s_waitcnt vmcnt(0)" ::: "memory");
        __syncthreads();
    }
    const float bh = bhh[jglob];

    // swizzled Wlds fragment read base; +kk*2048 elements per k-block
    const int ksw   = kchunk ^ ((frow >> 1) & 3);
    const bf16* wrd = Wlds + w * 512 + frow * 32 + ksw * 8;
    // Hlds fragment read base; +kk*64 bytes per k-block
    const char* hrd = Hlds + rr * 2064 + kchunk * 16;

    for (int t = 0; t < 128; ++t) {
        if (t > 0) {
            if (tid < 4)                     // parallel poll: 4 sub-counters x 4 adds
                while (__hip_atomic_load(&cnt[((t * 8 + group) * 4 + tid) * 32],
                                         __ATOMIC_RELAXED, __HIP_MEMORY_SCOPE_AGENT) < 4)
                    __builtin_amdgcn_s_sleep(1);
            __syncthreads();
        }
        // cooperative coherent fetch of group h_t (16KB): 256 thr x 8 x 8B, one window
        const ull* hsrc8 = (const ull*)(raw + (size_t)t * 65536 + group * 8192);
        ull hv[8];
        #pragma unroll
        for (int i = 0; i < 8; ++i)
            hv[i] = __hip_atomic_load(hsrc8 + tid + i * 256,
                                      __ATOMIC_RELAXED, __HIP_MEMORY_SCOPE_AGENT);
        // xw for this step from projection table P (latency hidden under h window)
        float xw[4];
        #pragma unroll
        for (int r = 0; r < 4; ++r) {
            const int bc  = (kchunk * 4 + r) & 7;
            const int tok = Tlds[t * 8 + bc];
            xw[r] = (float)P[(size_t)tok * 1024 + jglob];
        }
        #pragma unroll
        for (int i = 0; i < 8; ++i)
            *(ull*)(Hlds + i * 2064 + tid * 8) = hv[i];     // row i, chunk tid
        __syncthreads();

        f32x4 acc0 = {0.f,0.f,0.f,0.f}, acc1 = {0.f,0.f,0.f,0.f};
        #pragma unroll
        for (int kk = 0; kk < 32; kk += 2) {
            bf16x8 a0 = *(const bf16x8*)(hrd + kk * 64);
            bf16x8 a1 = *(const bf16x8*)(hrd + kk * 64 + 64);
            acc0 = __builtin_amdgcn_mfma_f32_16x16x32_bf16(a0, *(const bf16x8*)(wrd + kk * 2048),       acc0, 0, 0, 0);
            acc1 = __builtin_amdgcn_mfma_f32_16x16x32_bf16(a1, *(const bf16x8*)(wrd + (kk + 1) * 2048), acc1, 0, 0, 0);
        }

        bf16* rawN = raw + (size_t)(t + 1) * 65536;
        if (l < 32) {                               // rows 0-7 real
            #pragma unroll
            for (int r = 0; r < 4; ++r) {
                const int b = (l >> 4) * 4 + r;
                const float V = acc0[r] + acc1[r] + bh;             // h @ Whh^T + b_hh
                const float h = tanhf(xw[r] + V);                   // xw holds + b_ih
                const size_t row = (size_t)(t * 64 + group * 8 + b);
                Ust[row * 1024 + jglob] = (bf16)V;                  // hiddens_U (no b_ih)
                const bf16 hb = (bf16)h;
                unsigned short hs = __builtin_bit_cast(unsigned short, hb);
                unsigned short hn = (unsigned short)__shfl_down((int)hs, 1, 64);
                if ((frow & 1) == 0) {                              // pack 2 cols -> 4B store
                    unsigned int pack = (unsigned int)hs | ((unsigned int)hn << 16);
                    unsigned int* dst = (unsigned int*)(rawN + (size_t)(group * 8 + b) * 1024 + jglob);
                    __hip_atomic_store(dst, pack, __ATOMIC_RELAXED, __HIP_MEMORY_SCOPE_AGENT);
                }
            }
        }
        if (t < 127) {
            __syncthreads();                        // all waves' store acks drained here
            if (tid == 0)                           // relaxed: stores already at coherent pt
                __hip_atomic_fetch_add(&cnt[(((t + 1) * 8 + group) * 4 + (slot & 3)) * 32], 1,
                                       __ATOMIC_RELAXED, __HIP_MEMORY_SCOPE_AGENT);
        }
    }
}

// ---------------- pos term: (65/128) * sum (raw[t]-raw[t+1]+eps)^2 ----------------
__global__ void pos_kernel(const bf16* __restrict__ raw, float* __restrict__ lacc)
{
    float s = 0.f;
    const int NV = (128 * 64 * 1024) / 8;
    for (int i = blockIdx.x * blockDim.x + threadIdx.x; i < NV; i += gridDim.x * blockDim.x) {
        bf16x8 a = *(const bf16x8*)(raw + (size_t)i * 8);
        bf16x8 b = *(const bf16x8*)(raw + (size_t)i * 8 + 65536);
        #pragma unroll
        for (int j = 0; j < 8; ++j) {
            const float d = (float)a[j] - (float)b[j] + EPSC;
            s += d * d;
        }
    }
    #pragma unroll
    for (int off = 32; off > 0; off >>= 1) s += __shfl_down(s, off, 64);
    if ((threadIdx.x & 63) == 0) atomicAdd(lacc, s * (TEMPC / 128.f));
}

// ---------------- neg term: per row r, log(sum_s exp(-clip(||prev - tanh(P+U)||^2))) ---
// one wave per row (8192 waves = 2048 blocks x 4); pure gather-elementwise, no MFMA.
__global__ __launch_bounds__(256)
void neg_kernel(const int* __restrict__ samples, const bf16* __restrict__ P,
                const bf16* __restrict__ Ust, const bf16* __restrict__ raw,
                float* __restrict__ lacc)
{
    const int l = threadIdx.x & 63;
    const int r = blockIdx.x * 4 + (threadIdx.x >> 6);   // row 0..8191
    const bf16* u  = Ust + (size_t)r * 1024;
    const bf16* pv = raw + (size_t)r * 1024;

    float uf[16], vf[16];
    {
        bf16x8 u0 = *(const bf16x8*)(u + l * 8);
        bf16x8 u1 = *(const bf16x8*)(u + 512 + l * 8);
        bf16x8 v0 = *(const bf16x8*)(pv + l * 8);
        bf16x8 v1 = *(const bf16x8*)(pv + 512 + l * 8);
        #pragma unroll
        for (int i = 0; i < 8; ++i) {
            uf[i] = (float)u0[i]; uf[8 + i] = (float)u1[i];
            vf[i] = (float)v0[i]; vf[8 + i] = (float)v1[i];
        }
    }

    float se = 0.f;
    #pragma unroll
    for (int s = 0; s < 10; ++s) {
        const int tok = samples[s * 8192 + r];
        const bf16* pr = P + (size_t)tok * 1024;
        bf16x8 p0 = *(const bf16x8*)(pr + l * 8);
        bf16x8 p1 = *(const bf16x8*)(pr + 512 + l * 8);
        float d2 = 0.f;
        #pragma unroll
        for (int i = 0; i < 8; ++i) {
            const float o0 = tanhf((float)p0[i] + uf[i]);
            const float d0 = vf[i] - o0 + EPSC;
            d2 += d0 * d0;
            const float o1 = tanhf((float)p1[i] + uf[8 + i]);
            const float d1 = vf[8 + i] - o1 + EPSC;
            d2 += d1 * d1;
        }
        #pragma unroll
        for (int off = 1; off < 64; off <<= 1)
            d2 += __shfl_xor(d2, off, 64);
        se += expf(-fminf(d2, 0.01f));               // d2 >= 0 already
    }
    if (l == 0) atomicAdd(lacc, logf(se * (1.f / 8192.f) + EPSC));
}

// ---------------- finalize: copy accumulated loss ----------------
__global__ void fin_kernel(const float* __restrict__ lacc, float* __restrict__ out)
{
    if (threadIdx.x == 0) out[0] = lacc[0];
}

extern "C" void kernel_launch(void* const* d_in, const int* in_sizes, int n_in,
                              void* d_out, int out_size, void* d_ws, size_t ws_size,
                              hipStream_t stream)
{
    const int*   data    = (const int*)d_in[0];   // [128*64]
    const int*   samples = (const int*)d_in[1];   // [10*8192]
    const float* emb     = (const float*)d_in[2]; // [32000*1024]
    const float* Wih     = (const float*)d_in[3]; // [1024*1024]
    const float* bih     = (const float*)d_in[4]; // [1024]
    const float* Whh     = (const float*)d_in[5]; // [1024*1024]
    const float* bhh     = (const float*)d_in[6]; // [1024]

    char* ws = (char*)d_ws;
    size_t off = 0;
    auto alloc = [&](size_t bytes) { void* p = ws + off; off += (bytes + 255) & ~(size_t)255; return p; };
    bf16*  emb_b = (bf16*)alloc((size_t)32000 * 1024 * 2);
    bf16*  Wih_b = (bf16*)alloc((size_t)1024 * 1024 * 2);
    bf16*  Whh_b = (bf16*)alloc((size_t)1024 * 1024 * 2);
    bf16*  P     = (bf16*)alloc((size_t)32000 * 1024 * 2);
    bf16*  Ust   = (bf16*)alloc((size_t)8192 * 1024 * 2);
    bf16*  raw   = (bf16*)alloc((size_t)129 * 64 * 1024 * 2);
    float* lacc  = (float*)alloc(256);
    int*   cnt   = (int*)alloc(524288);

    hipMemsetAsync(raw,  0, 64 * 1024 * 2, stream);   // h0 = 0 (raw[0])
    hipMemsetAsync(lacc, 0, 256, stream);
    hipMemsetAsync(cnt,  0, 524288, stream);          // split step-barrier counters

    conv_kernel<<<2048, 256, 0, stream>>>(emb, emb_b, 32000 * 1024);
    conv_kernel<<<512, 256, 0, stream>>>(Wih, Wih_b, 1024 * 1024);
    conv_kernel<<<512, 256, 0, stream>>>(Whh, Whh_b, 1024 * 1024);

    // full-vocab projection table: P = emb @ Wih^T + b_ih
    pgemm_kernel<<<2000, 256, 0, stream>>>(emb_b, Wih_b, bih, P);

    // 128 RNN steps (xw gathered from P via data tokens)
    rnn_fused<<<128, 256, 0, stream>>>(data, raw, Whh_b, P, bhh, Ust, cnt);

    // pos term
    pos_kernel<<<512, 256, 0, stream>>>(raw, lacc);

    // neg term: gather-elementwise over samples (no GEMM)
    neg_kernel<<<2048, 256, 0, stream>>>(samples, P, Ust, raw, lacc);

    fin_kernel<<<1, 64, 0, stream>>>(lacc, (float*)d_out);
}